// Round 2
// baseline (8073.637 us; speedup 1.0000x reference)
//
#include <hip/hip_runtime.h>

#define H_ 160
#define W_ 160
#define HW 25600
#define L_ 51200
#define DM 128
#define DI 512
#define DS 256
#define NH 16
#define HD 32
#define CONVD 1024
#define DIP 1552
#define NCH 800      // number of chunks
#define NCH2 400     // chunks per half
#define EPSV 1e-5f

#define PADB 264     // ushort row stride for B/C tiles (256+8)

__device__ __forceinline__ float b2f(unsigned short u){
  union{unsigned int i; float f;} v; v.i = ((unsigned int)u) << 16; return v.f;
}
__device__ __forceinline__ unsigned short f2b(float f){
  union{unsigned int i; float f;} v; v.f = f;
  unsigned int r = v.i + 0x7fffu + ((v.i >> 16) & 1u);
  return (unsigned short)(r >> 16);
}

// ---------------------------------------------------------------- K0: coef
__global__ void k_coef(const float* __restrict__ opw, const float* __restrict__ nw,
                       float* __restrict__ coef){
  int i = blockIdx.x * blockDim.x + threadIdx.x;
  if (i >= DI) return;
  float s = 0.f;
  for (int j = 0; j < DM; ++j) s += opw[j * DI + i];
  coef[i] = (s / (float)DM) * nw[i];
}

// ---------------------------------------------------------------- K2: fc0 + in_proj GEMM + split
__global__ __launch_bounds__(256) void k_inproj(const float* __restrict__ x,
    const float* __restrict__ fw, const float* __restrict__ fb,
    const float* __restrict__ w, const float* __restrict__ dt_bias,
    unsigned short* __restrict__ g, unsigned short* __restrict__ xbcraw,
    float* __restrict__ dtb){
  __shared__ float us[64 * 132];
  __shared__ float xs[64 * 4];
  int c = blockIdx.x;          // 0..799, 64 rows each
  int l0 = c * 64;
  if (threadIdx.x < 64){
    int l = l0 + threadIdx.x;
    int i, j;
    if (l < HW){ i = l / W_; j = l % W_; }
    else { int l2 = l - HW; i = (H_ - 1) - l2 / W_; j = (W_ - 1) - l2 % W_; }
    int p = i * W_ + j;
    xs[threadIdx.x*4+0] = x[p];
    xs[threadIdx.x*4+1] = x[HW + p];
    xs[threadIdx.x*4+2] = x[2*HW + p];
  }
  __syncthreads();
  for (int e = threadIdx.x; e < 64 * 128; e += 256){
    int r = e >> 7, k = e & 127;
    us[r*132 + k] = fb[k] + fw[k*3+0]*xs[r*4+0] + fw[k*3+1]*xs[r*4+1] + fw[k*3+2]*xs[r*4+2];
  }
  __syncthreads();
  bool second = (c >= NCH2);
  int tl = threadIdx.x >> 2;   // 0..63 row
  int tj = threadIdx.x & 3;
  int l = l0 + tl;
  const float* ur = us + tl * 132;
  int jstart = second ? 0 : DI;   // first half never needs z
  for (int j = jstart + tj; j < DIP; j += 4){
    const float4* wr = reinterpret_cast<const float4*>(w + (size_t)j * DM);
    float acc = 0.f;
    #pragma unroll 8
    for (int q = 0; q < 32; ++q){
      float4 wv = wr[q];
      acc += ur[q*4+0]*wv.x + ur[q*4+1]*wv.y + ur[q*4+2]*wv.z + ur[q*4+3]*wv.w;
    }
    if (j < DI){
      float s = acc / (1.f + __expf(-acc));          // silu(z)
      g[(size_t)(l - HW) * DI + j] = f2b(s);
    } else if (j < DI + CONVD){
      xbcraw[(size_t)l * CONVD + (j - DI)] = f2b(acc);
    } else {
      int h = j - (DI + CONVD);
      float t = acc + dt_bias[h];
      float sp = (t > 20.f) ? t : log1pf(__expf(t));  // softplus
      dtb[(size_t)l * NH + h] = sp;
    }
  }
}

// ---------------------------------------------------------------- K3: depthwise causal conv + silu
__global__ void k_conv(const unsigned short* __restrict__ raw, const float* __restrict__ cw,
                       const float* __restrict__ cb, unsigned short* __restrict__ out){
  int idx = blockIdx.x * blockDim.x + threadIdx.x;
  if (idx >= L_ * CONVD) return;
  int l = idx >> 10, ch = idx & 1023;
  float4 wv = reinterpret_cast<const float4*>(cw)[ch];
  float acc = cb[ch];
  float vals[4];
  #pragma unroll
  for (int t = 0; t < 4; ++t){
    int ll = l - 3 + t;
    vals[t] = (ll >= 0) ? b2f(raw[(size_t)ll * CONVD + ch]) : 0.f;
  }
  acc += vals[0]*wv.x + vals[1]*wv.y + vals[2]*wv.z + vals[3]*wv.w;
  float s = acc / (1.f + __expf(-acc));
  out[idx] = f2b(s);
}

// ---------------------------------------------------------------- K4: per-chunk SSD core
// Processes chunks [cbase, cbase+gridDim.x); states written at LOCAL chunk index.
__global__ __launch_bounds__(256) void k_chunk(const unsigned short* __restrict__ xbc,
    const float* __restrict__ dtb, const float* __restrict__ A_log,
    unsigned short* __restrict__ states, float* __restrict__ atot,
    float* __restrict__ ecs, unsigned short* __restrict__ ydiag, int cbase){
  __shared__ unsigned short Bs[64 * PADB];
  __shared__ unsigned short Cs[64 * PADB];
  __shared__ float dts[64 * 16];    // [t*16+h]
  __shared__ float Acs[16 * 64];    // [h*64+t]
  __shared__ float G[64 * 66];
  __shared__ float M[64 * 66];
  __shared__ float xdt[64 * 33];
  __shared__ float xw[64 * 33];
  int cl = blockIdx.x;
  int c = cbase + cl;
  int l0 = c * 64;
  int tid = threadIdx.x;
  bool doY = (c >= NCH2);

  for (int i = tid; i < 64 * 16; i += 256) dts[i] = dtb[(size_t)l0 * NH + i];
  for (int r = 0; r < 64; ++r){
    Bs[r * PADB + tid] = xbc[(size_t)(l0 + r) * CONVD + DI + tid];
    Cs[r * PADB + tid] = xbc[(size_t)(l0 + r) * CONVD + DI + DS + tid];
  }
  __syncthreads();
  if (tid < 16){
    int h = tid;
    float Ah = -__expf(A_log[h]);
    float s = 0.f;
    for (int t = 0; t < 64; ++t){ s += dts[t*16 + h] * Ah; Acs[h*64 + t] = s; }
    atot[c * NH + h] = __expf(s);
  }
  __syncthreads();
  // G = C @ B^T (lower triangle)
  for (int e = tid * 16; e < tid * 16 + 16; ++e){
    int t = e >> 6, s2 = e & 63;
    if (s2 <= t){
      float acc = 0.f;
      const unsigned short* cr = Cs + t * PADB;
      const unsigned short* br = Bs + s2 * PADB;
      for (int n = 0; n < 256; ++n) acc += b2f(cr[n]) * b2f(br[n]);
      G[t * 66 + s2] = acc;
    }
  }
  for (int h = 0; h < NH; ++h){
    __syncthreads();  // protect xdt/xw/M reuse
    float alast = Acs[h*64 + 63];
    for (int i = tid; i < 2048; i += 256){
      int t = i >> 5, p = i & 31;
      float xv = b2f(xbc[(size_t)(l0 + t) * CONVD + h * HD + p]);
      float v = xv * dts[t*16 + h];
      xdt[t*33 + p] = v;
      xw[t*33 + p] = v * __expf(alast - Acs[h*64 + t]);
    }
    if (doY){
      for (int e = tid * 16; e < tid * 16 + 16; ++e){
        int t = e >> 6, s2 = e & 63;
        M[t*66 + s2] = (s2 <= t) ? G[t*66 + s2] * __expf(Acs[h*64 + t] - Acs[h*64 + s2]) : 0.f;
      }
    }
    __syncthreads();
    if (doY){
      for (int i = tid; i < 2048; i += 256){
        int t = i >> 5, p = i & 31;
        float acc = 0.f;
        const float* mr = M + t * 66;
        for (int s2 = 0; s2 <= t; ++s2) acc += mr[s2] * xdt[s2*33 + p];
        ydiag[(size_t)((l0 - HW) + t) * DI + h * HD + p] = f2b(acc);
      }
      if (tid < 64) ecs[((size_t)(c - NCH2) * NH + h) * 64 + tid] = __expf(Acs[h*64 + tid]);
    }
    for (int o = tid; o < 8192; o += 256){
      int p = o >> 8, n = o & 255;
      float acc = 0.f;
      for (int t = 0; t < 64; ++t) acc += b2f(Bs[t * PADB + n]) * xw[t*33 + p];
      states[(((size_t)cl * NH + h) * HD + p) * DS + n] = f2b(acc);
    }
  }
}

// ---------------------------------------------------------------- K5a: reduce first-half states -> carry at chunk 400
__global__ __launch_bounds__(256) void k_scanred(const unsigned short* __restrict__ states,
    const float* __restrict__ atot, float* __restrict__ carry){
  __shared__ float sat[NCH2];
  int idx = blockIdx.x * 256 + threadIdx.x;     // 0..131071, one (h,p,n)
  int h = idx >> 13;
  for (int c = threadIdx.x; c < NCH2; c += 256) sat[c] = atot[c * NH + h];
  __syncthreads();
  float cr = 0.f;
  const unsigned short* p = states + idx;
  for (int c = 0; c < NCH2; ++c){
    cr = sat[c] * cr + b2f(*p);
    p += 131072;
  }
  carry[idx] = cr;
}

// ---------------------------------------------------------------- K5b: in-place prefix over second-half states
__global__ __launch_bounds__(256) void k_scan2(unsigned short* __restrict__ states,
    const float* __restrict__ atot, const float* __restrict__ carry){
  __shared__ float sat[NCH2];
  int idx = blockIdx.x * 256 + threadIdx.x;
  int h = idx >> 13;
  for (int c = threadIdx.x; c < NCH2; c += 256) sat[c] = atot[(NCH2 + c) * NH + h];
  __syncthreads();
  float cr = carry[idx];
  unsigned short* p = states + idx;
  for (int c = 0; c < NCH2; ++c){
    float s = b2f(*p);
    *p = f2b(cr);
    cr = sat[c] * cr + s;
    p += 131072;
  }
}

// ---------------------------------------------------------------- K6: Y_off + skip + gate + sumsq
__global__ __launch_bounds__(256) void k_yoff(const unsigned short* __restrict__ xbc,
    const unsigned short* __restrict__ states, const float* __restrict__ ecs,
    const float* __restrict__ Dv, unsigned short* __restrict__ y,
    const unsigned short* __restrict__ g, float* __restrict__ rms){
  __shared__ unsigned short Cs[64 * PADB];
  __shared__ float Ss[32 * 257];
  __shared__ float ecs_s[NH * 64];
  __shared__ float Dv_s[NH];
  __shared__ float ssq[64];
  int c2 = blockIdx.x;           // 0..399 (local), chunk = c2 + 400
  int c = c2 + NCH2;
  int l0 = c * 64;
  int tid = threadIdx.x;
  for (int r = 0; r < 64; ++r)
    Cs[r * PADB + tid] = xbc[(size_t)(l0 + r) * CONVD + DI + DS + tid];
  for (int i = tid; i < NH * 64; i += 256) ecs_s[i] = ecs[(size_t)c2 * NH * 64 + i];
  if (tid < NH) Dv_s[tid] = Dv[tid];
  if (tid < 64) ssq[tid] = 0.f;
  float myss[8];
  #pragma unroll
  for (int k = 0; k < 8; ++k) myss[k] = 0.f;
  for (int h = 0; h < NH; ++h){
    __syncthreads();
    for (int i = tid; i < 8192; i += 256){
      int p = i >> 8, n = i & 255;
      Ss[p * 257 + n] = b2f(states[(((size_t)c2 * NH + h) * HD + p) * DS + n]);
    }
    __syncthreads();
    for (int i = tid; i < 2048; i += 256){
      int t = i >> 5, p = i & 31, k = i >> 8;
      float acc = 0.f;
      const unsigned short* cr = Cs + t * PADB;
      const float* sr = Ss + p * 257;
      for (int n = 0; n < 256; ++n) acc += b2f(cr[n]) * sr[n];
      float yo = ecs_s[h*64 + t] * acc;
      size_t oi = (size_t)(c2 * 64 + t) * DI + h * HD + p;
      float xh = b2f(xbc[(size_t)(l0 + t) * CONVD + h * HD + p]);
      float val = b2f(y[oi]) + yo + Dv_s[h] * xh;
      float yg = val * b2f(g[oi]);
      y[oi] = f2b(yg);
      myss[k] += yg * yg;
    }
  }
  __syncthreads();
  #pragma unroll
  for (int k = 0; k < 8; ++k) atomicAdd(&ssq[(tid >> 5) + 8 * k], myss[k]);
  __syncthreads();
  if (tid < 64) rms[c2 * 64 + tid] = rsqrtf(ssq[tid] / (float)DI + EPSV);
}

// ---------------------------------------------------------------- K7: half[l] = rms * (y . coef)
__global__ __launch_bounds__(256) void k_half(const unsigned short* __restrict__ yg,
    const float* __restrict__ rms, const float* __restrict__ coef,
    float* __restrict__ half_out){
  int wave = threadIdx.x >> 6, lane = threadIdx.x & 63;
  int row = blockIdx.x * 4 + wave;
  if (row >= HW) return;
  const unsigned short* yr = yg + (size_t)row * DI;
  float acc = 0.f;
  for (int i = lane; i < DI; i += 64) acc += b2f(yr[i]) * coef[i];
  #pragma unroll
  for (int off = 32; off; off >>= 1) acc += __shfl_down(acc, off, 64);
  if (lane == 0) half_out[row] = acc * rms[row];
}

// ---------------------------------------------------------------- K8: final fc1
__global__ __launch_bounds__(256) void k_fc1(const float* __restrict__ half_in,
    const float* __restrict__ w, const float* __restrict__ b, float* __restrict__ out){
  int k = blockIdx.x;
  const float* wr = w + (size_t)k * HW;
  float acc = 0.f;
  for (int i = threadIdx.x; i < HW; i += 256) acc += half_in[i] * wr[i];
  __shared__ float red[256];
  red[threadIdx.x] = acc;
  __syncthreads();
  for (int s = 128; s; s >>= 1){
    if (threadIdx.x < s) red[threadIdx.x] += red[threadIdx.x + s];
    __syncthreads();
  }
  if (threadIdx.x == 0) out[k] = red[0] + b[k];
}

// ---------------------------------------------------------------- launch
extern "C" void kernel_launch(void* const* d_in, const int* in_sizes, int n_in,
                              void* d_out, int out_size, void* d_ws, size_t ws_size,
                              hipStream_t stream){
  const float* x      = (const float*)d_in[0];
  const float* fc0_w  = (const float*)d_in[1];
  const float* fc0_b  = (const float*)d_in[2];
  const float* ipw    = (const float*)d_in[3];
  const float* conv_w = (const float*)d_in[4];
  const float* conv_b = (const float*)d_in[5];
  const float* dt_bias= (const float*)d_in[6];
  const float* A_log  = (const float*)d_in[7];
  const float* Dv     = (const float*)d_in[8];
  const float* norm_w = (const float*)d_in[9];
  const float* opw    = (const float*)d_in[10];
  const float* fc1_w  = (const float*)d_in[11];
  const float* fc1_b  = (const float*)d_in[12];
  float* out = (float*)d_out;

  char* ws = (char*)d_ws;
  size_t off = 0;
  float* dtb          = (float*)(ws + off);           off += (size_t)L_ * NH * 4;          // 3.3 MB
  unsigned short* stx = (unsigned short*)(ws + off);  off += (size_t)L_ * CONVD * 2;       // 104.9 MB (xraw, then aliased as 400-chunk state buf)
  unsigned short* xbc = (unsigned short*)(ws + off);  off += (size_t)L_ * CONVD * 2;       // 104.9 MB
  unsigned short* g   = (unsigned short*)(ws + off);  off += (size_t)HW * DI * 2;          // 26.2 MB
  unsigned short* yd  = (unsigned short*)(ws + off);  off += (size_t)HW * DI * 2;          // 26.2 MB
  float* atot         = (float*)(ws + off);           off += (size_t)NCH * NH * 4;
  float* ecs          = (float*)(ws + off);           off += (size_t)NCH2 * NH * 64 * 4;
  float* rms          = (float*)(ws + off);           off += (size_t)HW * 4;
  float* half_buf     = (float*)(ws + off);           off += (size_t)HW * 4;
  float* coef         = (float*)(ws + off);           off += (size_t)DI * 4;
  float* carry        = (float*)(ws + off);           off += (size_t)131072 * 4;

  if (ws_size < off) return;   // diagnostic guard: insufficient scratch -> all-zero output

  k_coef   <<<2, 256, 0, stream>>>(opw, norm_w, coef);
  k_inproj <<<NCH, 256, 0, stream>>>(x, fc0_w, fc0_b, ipw, dt_bias, g, stx, dtb);
  k_conv   <<<(L_ * CONVD) / 256, 256, 0, stream>>>(stx, conv_w, conv_b, xbc);
  // xraw (stx) dead from here; reuse region as the 400-chunk state buffer
  k_chunk  <<<NCH2, 256, 0, stream>>>(xbc, dtb, A_log, stx, atot, ecs, yd, 0);
  k_scanred<<<512, 256, 0, stream>>>(stx, atot, carry);
  k_chunk  <<<NCH2, 256, 0, stream>>>(xbc, dtb, A_log, stx, atot, ecs, yd, NCH2);
  k_scan2  <<<512, 256, 0, stream>>>(stx, atot, carry);
  k_yoff   <<<NCH2, 256, 0, stream>>>(xbc, stx, ecs, Dv, yd, g, rms);
  k_half   <<<HW / 4, 256, 0, stream>>>(yd, rms, coef, half_buf);
  k_fc1    <<<DM, 256, 0, stream>>>(half_buf, fc1_w, fc1_b, out);
}

// Round 4
// 716.383 us; speedup vs baseline: 11.2700x; 11.2700x over previous
//
#include <hip/hip_runtime.h>

#define H_ 160
#define W_ 160
#define HW 25600
#define L_ 51200
#define DM 128
#define DI 512
#define DS 256
#define NH 16
#define HD 32
#define CONVD 1024
#define DIP 1552
#define NCH 800      // number of chunks
#define NCH2 400     // chunks per half
#define EPSV 1e-5f

typedef __attribute__((ext_vector_type(8))) short bf16x8;
typedef __attribute__((ext_vector_type(8))) unsigned short us8;
typedef __attribute__((ext_vector_type(4))) float f32x4;
#define MFMA16(a,b,c) __builtin_amdgcn_mfma_f32_16x16x32_bf16(a,b,c,0,0,0)

__device__ __forceinline__ float b2f(unsigned short u){
  union{unsigned int i; float f;} v; v.i = ((unsigned int)u) << 16; return v.f;
}
__device__ __forceinline__ unsigned short f2b(float f){
  union{unsigned int i; float f;} v; v.f = f;
  unsigned int r = v.i + 0x7fffu + ((v.i >> 16) & 1u);
  return (unsigned short)(r >> 16);
}
__device__ __forceinline__ short f2bs(float f){ return (short)f2b(f); }

// ---------------------------------------------------------------- K0: coef
__global__ void k_coef(const float* __restrict__ opw, const float* __restrict__ nw,
                       float* __restrict__ coef){
  int i = blockIdx.x * blockDim.x + threadIdx.x;
  if (i >= DI) return;
  float s = 0.f;
  for (int j = 0; j < DM; ++j) s += opw[j * DI + i];
  coef[i] = (s / (float)DM) * nw[i];
}

// ---------------------------------------------------------------- K0b: w -> bf16
__global__ void k_wcvt(const float* __restrict__ w, unsigned short* __restrict__ wb){
  int i = blockIdx.x * 256 + threadIdx.x;
  if (i < DIP * DM) wb[i] = f2b(w[i]);
}

// ---------------------------------------------------------------- K2: fc0 + in_proj (MFMA)
// Each wave holds A-fragments for ALL 4 row-tiles; column tiles split across waves.
// dt path (cols 1536..1551) computed in f32 thread-level math for precision.
__global__ __launch_bounds__(256) void k_inproj(const float* __restrict__ x,
    const float* __restrict__ fw, const float* __restrict__ fb,
    const float* __restrict__ wf32, const unsigned short* __restrict__ wbf,
    const float* __restrict__ dt_bias,
    unsigned short* __restrict__ g, unsigned short* __restrict__ xbcraw,
    float* __restrict__ dtb){
  __shared__ float us[64 * 132];
  int c = blockIdx.x;          // 0..799, 64 rows each
  int l0 = c * 64;
  int lane = threadIdx.x & 63, wv = threadIdx.x >> 6;
  int kg = lane >> 4, l15 = lane & 15;
  bf16x8 afr[4][4];            // [row-tile][k-step]
  #pragma unroll
  for (int rt = 0; rt < 4; ++rt){
    int lrow = l0 + rt * 16 + l15;
    int pi, pj;
    if (lrow < HW){ pi = lrow / W_; pj = lrow % W_; }
    else { int l2 = lrow - HW; pi = (H_ - 1) - l2 / W_; pj = (W_ - 1) - l2 % W_; }
    int p = pi * W_ + pj;
    float x0 = x[p], x1 = x[HW + p], x2 = x[2 * HW + p];
    #pragma unroll
    for (int s = 0; s < 4; ++s){
      bf16x8 t;
      #pragma unroll
      for (int e = 0; e < 8; ++e){
        int k = s * 32 + kg * 8 + e;
        float v = fb[k] + fw[k*3+0]*x0 + fw[k*3+1]*x1 + fw[k*3+2]*x2;
        if (wv == 0) us[(rt * 16 + l15) * 132 + k] = v;   // wave0's kg-groups cover all k
        t[e] = f2bs(v);
      }
      afr[rt][s] = t;
    }
  }
  __syncthreads();
  // dt in f32
  for (int idx = threadIdx.x; idx < 1024; idx += 256){
    int r = idx >> 4, h = idx & 15;
    const float* wr = wf32 + (size_t)(DI + CONVD + h) * DM;
    const float* ur = us + r * 132;
    float acc = 0.f;
    #pragma unroll 4
    for (int k = 0; k < DM; ++k) acc += ur[k] * wr[k];
    float tv = acc + dt_bias[h];
    float sp = (tv > 20.f) ? tv : log1pf(__expf(tv));
    dtb[(size_t)(l0 + r) * NH + h] = sp;
  }
  // z / xBC via MFMA
  int jt0 = (c < NCH2) ? 32 : 0;     // first half never needs z
  for (int jt = jt0 + wv; jt < 96; jt += 4){
    const unsigned short* wb = wbf + (size_t)(jt * 16 + l15) * DM + kg * 8;
    bf16x8 bfrag[4];
    #pragma unroll
    for (int s = 0; s < 4; ++s) bfrag[s] = *reinterpret_cast<const bf16x8*>(wb + s * 32);
    #pragma unroll
    for (int rt = 0; rt < 4; ++rt){
      f32x4 acc = {0.f, 0.f, 0.f, 0.f};
      #pragma unroll
      for (int s = 0; s < 4; ++s) acc = MFMA16(afr[rt][s], bfrag[s], acc);
      int rbase = l0 + rt * 16 + kg * 4;
      if (jt < 32){
        #pragma unroll
        for (int r = 0; r < 4; ++r){
          float v = acc[r];
          float sg = v / (1.f + __expf(-v));      // silu(z)
          g[(size_t)(rbase + r - HW) * DI + jt * 16 + l15] = f2b(sg);
        }
      } else {
        #pragma unroll
        for (int r = 0; r < 4; ++r)
          xbcraw[(size_t)(rbase + r) * CONVD + (jt - 32) * 16 + l15] = f2b(acc[r]);
      }
    }
  }
}

// ---------------------------------------------------------------- K3: depthwise causal conv + silu
__global__ void k_conv(const unsigned short* __restrict__ raw, const float* __restrict__ cw,
                       const float* __restrict__ cb, unsigned short* __restrict__ out){
  int idx = blockIdx.x * blockDim.x + threadIdx.x;
  if (idx >= L_ * CONVD) return;
  int l = idx >> 10, ch = idx & 1023;
  float4 wv = reinterpret_cast<const float4*>(cw)[ch];
  float acc = cb[ch];
  float vals[4];
  #pragma unroll
  for (int t = 0; t < 4; ++t){
    int ll = l - 3 + t;
    vals[t] = (ll >= 0) ? b2f(raw[(size_t)ll * CONVD + ch]) : 0.f;
  }
  acc += vals[0]*wv.x + vals[1]*wv.y + vals[2]*wv.z + vals[3]*wv.w;
  float s = acc / (1.f + __expf(-acc));
  out[idx] = f2b(s);
}

// ---------------------------------------------------------------- K4: per-chunk SSD core (MFMA)
__global__ __launch_bounds__(256) void k_chunk(const unsigned short* __restrict__ xbc,
    const float* __restrict__ dtb, const float* __restrict__ A_log,
    unsigned short* __restrict__ states, float* __restrict__ atot,
    float* __restrict__ ecs, unsigned short* __restrict__ ydiag, int cbase){
  __shared__ char U[65536];          // Bs[0,32K) Cs[32K,64K) -> then M/xdtT/xwT
  __shared__ float dts[1024];        // [t*16+h]
  __shared__ float Acs[1024];        // [h*64+t]
  unsigned short* Bs = (unsigned short*)U;
  unsigned short* Cs = (unsigned short*)(U + 32768);
  char* Mb  = U;                     // [64][64] bf16 swizzled (8KB)
  char* xdT = U + 8192;              // [32][64] bf16 swizzled (4KB)
  char* xwT = U + 12288;             // [32][64] bf16 swizzled (4KB)
  int cl = blockIdx.x, c = cbase + cl, l0 = c * 64;
  int tid = threadIdx.x, lane = tid & 63, wv = tid >> 6;
  int kg = lane >> 4, l15 = lane & 15;
  bool doY = (c >= NCH2);

  for (int i = tid; i < 1024; i += 256) dts[i] = dtb[(size_t)l0 * NH + i];
  #pragma unroll
  for (int it = 0; it < 8; ++it){
    int r = (tid >> 5) + 8 * it, c8 = tid & 31;
    uint4 v = *reinterpret_cast<const uint4*>(xbc + (size_t)(l0 + r) * CONVD + DI + c8 * 8);
    *reinterpret_cast<uint4*>((char*)Bs + ((r * 512 + c8 * 16) ^ ((r & 7) << 4))) = v;
    if (doY){
      uint4 v2 = *reinterpret_cast<const uint4*>(xbc + (size_t)(l0 + r) * CONVD + DI + DS + c8 * 8);
      *reinterpret_cast<uint4*>((char*)Cs + ((r * 512 + c8 * 16) ^ ((r & 7) << 4))) = v2;
    }
  }
  __syncthreads();
  if (tid < 16){
    int h = tid; float Ah = -__expf(A_log[h]); float s = 0.f;
    for (int t = 0; t < 64; ++t){ s += dts[t*16 + h] * Ah; Acs[h*64 + t] = s; }
    atot[c * NH + h] = __expf(s);
  }
  // B^T fragments for the state GEMM (k = t), kept in registers for all h
  bf16x8 bst[8];     // [nt*2 + s]
  #pragma unroll
  for (int nt = 0; nt < 4; ++nt)
    #pragma unroll
    for (int s = 0; s < 2; ++s){
      int n = wv * 64 + nt * 16 + l15;
      int tb = s * 32 + kg * 8;
      bf16x8 f;
      #pragma unroll
      for (int e = 0; e < 8; ++e){
        int t = tb + e;
        f[e] = *reinterpret_cast<const short*>((char*)Bs + ((t * 512 + n * 2) ^ ((t & 7) << 4)));
      }
      bst[nt * 2 + s] = f;
    }
  // G = C.B^T (this wave's 16-row t-tile x all 64 s), registers
  f32x4 Gacc[4];
  if (doY){
    #pragma unroll
    for (int st = 0; st < 4; ++st) Gacc[st] = (f32x4){0.f,0.f,0.f,0.f};
    int trow = wv * 16 + l15;
    for (int ks = 0; ks < 8; ++ks){
      bf16x8 a = *reinterpret_cast<const bf16x8*>((char*)Cs + ((trow * 512 + (ks*32 + kg*8) * 2) ^ ((trow & 7) << 4)));
      #pragma unroll
      for (int st = 0; st < 4; ++st){
        int srow = st * 16 + l15;
        bf16x8 b = *reinterpret_cast<const bf16x8*>((char*)Bs + ((srow * 512 + (ks*32 + kg*8) * 2) ^ ((srow & 7) << 4)));
        Gacc[st] = MFMA16(a, b, Gacc[st]);
      }
    }
  }
  __syncthreads();     // Bs/Cs now dead; Acs ready
  for (int h = 0; h < NH; ++h){
    float alast = Acs[h*64 + 63];
    {  // write xdt^T, xw^T  [p][t] bf16 swizzled
      int t = tid & 63, pb = tid >> 6;
      float dtv = dts[t*16 + h];
      float dec = __expf(alast - Acs[h*64 + t]);
      us8 x8 = *reinterpret_cast<const us8*>(xbc + (size_t)(l0 + t) * CONVD + h * HD + pb * 8);
      #pragma unroll
      for (int e = 0; e < 8; ++e){
        int pp = pb * 8 + e;
        float v = b2f(x8[e]) * dtv;
        *reinterpret_cast<unsigned short*>(xdT + ((pp * 128 + t * 2) ^ ((pp & 7) << 4))) = f2b(v);
        *reinterpret_cast<unsigned short*>(xwT + ((pp * 128 + t * 2) ^ ((pp & 7) << 4))) = f2b(v * dec);
      }
    }
    if (doY){
      #pragma unroll
      for (int st = 0; st < 4; ++st)
        #pragma unroll
        for (int r = 0; r < 4; ++r){
          int t = wv * 16 + kg * 4 + r, s2 = st * 16 + l15;
          float m = (s2 <= t) ? Gacc[st][r] * __expf(Acs[h*64 + t] - Acs[h*64 + s2]) : 0.f;
          *reinterpret_cast<unsigned short*>(Mb + ((t * 128 + s2 * 2) ^ ((t & 7) << 4))) = f2b(m);
        }
      if (tid < 64) ecs[((size_t)(c - NCH2) * NH + h) * 64 + tid] = __expf(Acs[h*64 + tid]);
    }
    __syncthreads();
    {  // states[p][n] = sum_t xw^T[p][t] * B[t][n]
      f32x4 sacc[2][4];
      #pragma unroll
      for (int mt = 0; mt < 2; ++mt)
        #pragma unroll
        for (int nt = 0; nt < 4; ++nt) sacc[mt][nt] = (f32x4){0.f,0.f,0.f,0.f};
      #pragma unroll
      for (int s = 0; s < 2; ++s)
        #pragma unroll
        for (int mt = 0; mt < 2; ++mt){
          int pr = mt * 16 + l15;
          bf16x8 a = *reinterpret_cast<const bf16x8*>(xwT + ((pr * 128 + (s*32 + kg*8) * 2) ^ ((pr & 7) << 4)));
          #pragma unroll
          for (int nt = 0; nt < 4; ++nt) sacc[mt][nt] = MFMA16(a, bst[nt*2 + s], sacc[mt][nt]);
        }
      #pragma unroll
      for (int mt = 0; mt < 2; ++mt)
        #pragma unroll
        for (int nt = 0; nt < 4; ++nt)
          #pragma unroll
          for (int r = 0; r < 4; ++r){
            int pp = mt * 16 + kg * 4 + r, n = wv * 64 + nt * 16 + l15;
            states[(((size_t)cl * NH + h) * HD + pp) * DS + n] = f2b(sacc[mt][nt][r]);
          }
    }
    if (doY){  // Y_diag[t][p] = sum_s M[t][s] * xdt^T[p][s]
      f32x4 yacc[2];
      yacc[0] = (f32x4){0.f,0.f,0.f,0.f}; yacc[1] = (f32x4){0.f,0.f,0.f,0.f};
      int trow = wv * 16 + l15;
      #pragma unroll
      for (int s = 0; s < 2; ++s){
        bf16x8 a = *reinterpret_cast<const bf16x8*>(Mb + ((trow * 128 + (s*32 + kg*8) * 2) ^ ((trow & 7) << 4)));
        #pragma unroll
        for (int pt = 0; pt < 2; ++pt){
          int pr = pt * 16 + l15;
          bf16x8 b = *reinterpret_cast<const bf16x8*>(xdT + ((pr * 128 + (s*32 + kg*8) * 2) ^ ((pr & 7) << 4)));
          yacc[pt] = MFMA16(a, b, yacc[pt]);
        }
      }
      #pragma unroll
      for (int pt = 0; pt < 2; ++pt)
        #pragma unroll
        for (int r = 0; r < 4; ++r){
          int t = wv * 16 + kg * 4 + r, pp = pt * 16 + l15;
          ydiag[(size_t)(l0 - HW + t) * DI + h * HD + pp] = f2b(yacc[pt][r]);
        }
    }
    __syncthreads();
  }
}

// ---------------------------------------------------------------- K5a: reduce first-half states -> carry
__global__ __launch_bounds__(256) void k_scanred(const unsigned short* __restrict__ states,
    const float* __restrict__ atot, float* __restrict__ carry){
  __shared__ float sat[NCH2];
  int idx = blockIdx.x * 256 + threadIdx.x;     // 0..131071, one (h,p,n)
  int h = idx >> 13;
  for (int c = threadIdx.x; c < NCH2; c += 256) sat[c] = atot[c * NH + h];
  __syncthreads();
  float cr = 0.f;
  const unsigned short* p = states + idx;
  for (int c = 0; c < NCH2; ++c){
    cr = sat[c] * cr + b2f(*p);
    p += 131072;
  }
  carry[idx] = cr;
}

// ---------------------------------------------------------------- K5b: in-place prefix over second-half states
__global__ __launch_bounds__(256) void k_scan2(unsigned short* __restrict__ states,
    const float* __restrict__ atot, const float* __restrict__ carry){
  __shared__ float sat[NCH2];
  int idx = blockIdx.x * 256 + threadIdx.x;
  int h = idx >> 13;
  for (int c = threadIdx.x; c < NCH2; c += 256) sat[c] = atot[(NCH2 + c) * NH + h];
  __syncthreads();
  float cr = carry[idx];
  unsigned short* p = states + idx;
  for (int c = 0; c < NCH2; ++c){
    float s = b2f(*p);
    *p = f2b(cr);
    cr = sat[c] * cr + s;
    p += 131072;
  }
}

// ---------------------------------------------------------------- K6: Y_off + skip + gate + sumsq (MFMA)
__global__ __launch_bounds__(256) void k_yoff(const unsigned short* __restrict__ xbc,
    const unsigned short* __restrict__ states, const float* __restrict__ ecs,
    const float* __restrict__ Dv, unsigned short* __restrict__ y,
    const unsigned short* __restrict__ g, float* __restrict__ rms){
  __shared__ unsigned short Cs[64 * 256];   // swizzled
  __shared__ float ecs_s[1024];             // [h*64+t]
  int c2 = blockIdx.x;           // 0..399 (local), chunk = c2 + 400
  int c = c2 + NCH2, l0 = c * 64;
  int tid = threadIdx.x, lane = tid & 63, wv = tid >> 6;
  int kg = lane >> 4, l15 = lane & 15;
  #pragma unroll
  for (int it = 0; it < 8; ++it){
    int r = (tid >> 5) + 8 * it, c8 = tid & 31;
    uint4 v = *reinterpret_cast<const uint4*>(xbc + (size_t)(l0 + r) * CONVD + DI + DS + c8 * 8);
    *reinterpret_cast<uint4*>((char*)Cs + ((r * 512 + c8 * 16) ^ ((r & 7) << 4))) = v;
  }
  for (int i = tid; i < 1024; i += 256) ecs_s[i] = ecs[(size_t)c2 * 1024 + i];
  __syncthreads();
  bf16x8 aC[8];
  int trow = wv * 16 + l15;
  #pragma unroll
  for (int ks = 0; ks < 8; ++ks)
    aC[ks] = *reinterpret_cast<const bf16x8*>((char*)Cs + ((trow * 512 + (ks*32 + kg*8) * 2) ^ ((trow & 7) << 4)));
  float rowsq[4] = {0.f, 0.f, 0.f, 0.f};
  for (int h = 0; h < NH; ++h){
    f32x4 acc[2];
    acc[0] = (f32x4){0.f,0.f,0.f,0.f}; acc[1] = (f32x4){0.f,0.f,0.f,0.f};
    const unsigned short* sb = states + ((size_t)c2 * NH + h) * HD * DS;
    #pragma unroll
    for (int ks = 0; ks < 8; ++ks)
      #pragma unroll
      for (int pt = 0; pt < 2; ++pt){
        bf16x8 b = *reinterpret_cast<const bf16x8*>(sb + (pt * 16 + l15) * DS + ks * 32 + kg * 8);
        acc[pt] = MFMA16(aC[ks], b, acc[pt]);
      }
    float Dh = Dv[h];
    #pragma unroll
    for (int pt = 0; pt < 2; ++pt)
      #pragma unroll
      for (int r = 0; r < 4; ++r){
        int t = wv * 16 + kg * 4 + r, pp = pt * 16 + l15;
        size_t oi = (size_t)(c2 * 64 + t) * DI + h * HD + pp;
        float xh = b2f(xbc[(size_t)(l0 + t) * CONVD + h * HD + pp]);
        float val = b2f(y[oi]) + ecs_s[h*64 + t] * acc[pt][r] + Dh * xh;
        float yg = val * b2f(g[oi]);
        y[oi] = f2b(yg);
        rowsq[r] += yg * yg;
      }
  }
  #pragma unroll
  for (int r = 0; r < 4; ++r){
    float v = rowsq[r];
    v += __shfl_xor(v, 1, 16);
    v += __shfl_xor(v, 2, 16);
    v += __shfl_xor(v, 4, 16);
    v += __shfl_xor(v, 8, 16);
    if (l15 == 0){
      int t = wv * 16 + kg * 4 + r;
      rms[c2 * 64 + t] = rsqrtf(v / (float)DI + EPSV);
    }
  }
}

// ---------------------------------------------------------------- K7: half[l] = rms * (y . coef)
__global__ __launch_bounds__(256) void k_half(const unsigned short* __restrict__ yg,
    const float* __restrict__ rms, const float* __restrict__ coef,
    float* __restrict__ half_out){
  int wave = threadIdx.x >> 6, lane = threadIdx.x & 63;
  int row = blockIdx.x * 4 + wave;
  if (row >= HW) return;
  const unsigned short* yr = yg + (size_t)row * DI;
  float acc = 0.f;
  for (int i = lane; i < DI; i += 64) acc += b2f(yr[i]) * coef[i];
  #pragma unroll
  for (int off = 32; off; off >>= 1) acc += __shfl_down(acc, off, 64);
  if (lane == 0) half_out[row] = acc * rms[row];
}

// ---------------------------------------------------------------- K8: final fc1
__global__ __launch_bounds__(256) void k_fc1(const float* __restrict__ half_in,
    const float* __restrict__ w, const float* __restrict__ b, float* __restrict__ out){
  int k = blockIdx.x;
  const float* wr = w + (size_t)k * HW;
  float acc = 0.f;
  for (int i = threadIdx.x; i < HW; i += 256) acc += half_in[i] * wr[i];
  __shared__ float red[256];
  red[threadIdx.x] = acc;
  __syncthreads();
  for (int s = 128; s; s >>= 1){
    if (threadIdx.x < s) red[threadIdx.x] += red[threadIdx.x + s];
    __syncthreads();
  }
  if (threadIdx.x == 0) out[k] = red[0] + b[k];
}

// ---------------------------------------------------------------- launch
extern "C" void kernel_launch(void* const* d_in, const int* in_sizes, int n_in,
                              void* d_out, int out_size, void* d_ws, size_t ws_size,
                              hipStream_t stream){
  const float* x      = (const float*)d_in[0];
  const float* fc0_w  = (const float*)d_in[1];
  const float* fc0_b  = (const float*)d_in[2];
  const float* ipw    = (const float*)d_in[3];
  const float* conv_w = (const float*)d_in[4];
  const float* conv_b = (const float*)d_in[5];
  const float* dt_bias= (const float*)d_in[6];
  const float* A_log  = (const float*)d_in[7];
  const float* Dv     = (const float*)d_in[8];
  const float* norm_w = (const float*)d_in[9];
  const float* opw    = (const float*)d_in[10];
  const float* fc1_w  = (const float*)d_in[11];
  const float* fc1_b  = (const float*)d_in[12];
  float* out = (float*)d_out;

  char* ws = (char*)d_ws;
  size_t off = 0;
  float* dtb          = (float*)(ws + off);           off += (size_t)L_ * NH * 4;          // 3.3 MB
  unsigned short* stx = (unsigned short*)(ws + off);  off += (size_t)L_ * CONVD * 2;       // 104.9 MB (xraw, then 400-chunk states)
  unsigned short* xbc = (unsigned short*)(ws + off);  off += (size_t)L_ * CONVD * 2;       // 104.9 MB
  unsigned short* g   = (unsigned short*)(ws + off);  off += (size_t)HW * DI * 2;          // 26.2 MB
  unsigned short* yd  = (unsigned short*)(ws + off);  off += (size_t)HW * DI * 2;          // 26.2 MB
  float* atot         = (float*)(ws + off);           off += (size_t)NCH * NH * 4;
  float* ecs          = (float*)(ws + off);           off += (size_t)NCH2 * NH * 64 * 4;
  float* rms          = (float*)(ws + off);           off += (size_t)HW * 4;
  float* half_buf     = (float*)(ws + off);           off += (size_t)HW * 4;
  float* coef         = (float*)(ws + off);           off += (size_t)DI * 4;
  float* carry        = (float*)(ws + off);           off += (size_t)131072 * 4;
  unsigned short* wbf16 = (unsigned short*)carry;     // alias: wbf16 dead before carry is written

  if (ws_size < off) return;   // diagnostic guard

  k_coef   <<<2, 256, 0, stream>>>(opw, norm_w, coef);
  k_wcvt   <<<(DIP * DM + 255) / 256, 256, 0, stream>>>(ipw, wbf16);
  k_inproj <<<NCH, 256, 0, stream>>>(x, fc0_w, fc0_b, ipw, wbf16, dt_bias, g, stx, dtb);
  k_conv   <<<(L_ * CONVD) / 256, 256, 0, stream>>>(stx, conv_w, conv_b, xbc);
  // stx dead; reuse as 400-chunk state buffer
  k_chunk  <<<NCH2, 256, 0, stream>>>(xbc, dtb, A_log, stx, atot, ecs, yd, 0);
  k_scanred<<<512, 256, 0, stream>>>(stx, atot, carry);
  k_chunk  <<<NCH2, 256, 0, stream>>>(xbc, dtb, A_log, stx, atot, ecs, yd, NCH2);
  k_scan2  <<<512, 256, 0, stream>>>(stx, atot, carry);
  k_yoff   <<<NCH2, 256, 0, stream>>>(xbc, stx, ecs, Dv, yd, g, rms);
  k_half   <<<HW / 4, 256, 0, stream>>>(yd, rms, coef, half_buf);
  k_fc1    <<<DM, 256, 0, stream>>>(half_buf, fc1_w, fc1_b, out);
}

// Round 5
// 656.564 us; speedup vs baseline: 12.2968x; 1.0911x over previous
//
#include <hip/hip_runtime.h>

#define H_ 160
#define W_ 160
#define HW 25600
#define L_ 51200
#define DM 128
#define DI 512
#define DS 256
#define NH 16
#define HD 32
#define CONVD 1024
#define DIP 1552
#define NCH 800      // number of chunks
#define NCH2 400     // chunks per half
#define EPSV 1e-5f

typedef __attribute__((ext_vector_type(8))) short bf16x8;
typedef __attribute__((ext_vector_type(8))) unsigned short us8;
typedef __attribute__((ext_vector_type(4))) unsigned short us4;
typedef __attribute__((ext_vector_type(4))) float f32x4;
#define MFMA16(a,b,c) __builtin_amdgcn_mfma_f32_16x16x32_bf16(a,b,c,0,0,0)

__device__ __forceinline__ float b2f(unsigned short u){
  union{unsigned int i; float f;} v; v.i = ((unsigned int)u) << 16; return v.f;
}
__device__ __forceinline__ unsigned short f2b(float f){
  union{unsigned int i; float f;} v; v.f = f;
  unsigned int r = v.i + 0x7fffu + ((v.i >> 16) & 1u);
  return (unsigned short)(r >> 16);
}
__device__ __forceinline__ short f2bs(float f){ return (short)f2b(f); }

// ---------------------------------------------------------------- K0: coef
__global__ void k_coef(const float* __restrict__ opw, const float* __restrict__ nw,
                       float* __restrict__ coef){
  int i = blockIdx.x * blockDim.x + threadIdx.x;
  if (i >= DI) return;
  float s = 0.f;
  for (int j = 0; j < DM; ++j) s += opw[j * DI + i];
  coef[i] = (s / (float)DM) * nw[i];
}

// ---------------------------------------------------------------- K0b: w -> bf16
__global__ void k_wcvt(const float* __restrict__ w, unsigned short* __restrict__ wb){
  int i = blockIdx.x * 256 + threadIdx.x;
  if (i < DIP * DM) wb[i] = f2b(w[i]);
}

// ---------------------------------------------------------------- K2: fc0 + in_proj (MFMA, LDS-staged stores)
__global__ __launch_bounds__(256) void k_inproj(const float* __restrict__ x,
    const float* __restrict__ fw, const float* __restrict__ fb,
    const float* __restrict__ wf32, const unsigned short* __restrict__ wbf,
    const float* __restrict__ dt_bias,
    unsigned short* __restrict__ g, unsigned short* __restrict__ xbcraw,
    float* __restrict__ dtb){
  __shared__ float us[64 * 132];          // 33792 B; aliased as stage after dt phase
  __shared__ float wdt[16 * 132];         // dt weight rows, padded
  unsigned short* stage = (unsigned short*)us;   // [64][72] ushort = 9216 B
  int c = blockIdx.x;          // 0..799, 64 rows each
  int l0 = c * 64;
  int tid = threadIdx.x, lane = tid & 63, wv = tid >> 6;
  int kg = lane >> 4, l15 = lane & 15;
  // Phase A: fc0 into A-fragments (all 4 row-tiles per wave) + f32 u rows to LDS
  bf16x8 afr[4][4];            // [row-tile][k-step]
  #pragma unroll
  for (int rt = 0; rt < 4; ++rt){
    int lrow = l0 + rt * 16 + l15;
    int pi, pj;
    if (lrow < HW){ pi = lrow / W_; pj = lrow % W_; }
    else { int l2 = lrow - HW; pi = (H_ - 1) - l2 / W_; pj = (W_ - 1) - l2 % W_; }
    int p = pi * W_ + pj;
    float x0 = x[p], x1 = x[HW + p], x2 = x[2 * HW + p];
    #pragma unroll
    for (int s = 0; s < 4; ++s){
      bf16x8 t;
      #pragma unroll
      for (int e = 0; e < 8; ++e){
        int k = s * 32 + kg * 8 + e;
        float v = fb[k] + fw[k*3+0]*x0 + fw[k*3+1]*x1 + fw[k*3+2]*x2;
        if (wv == 0) us[(rt * 16 + l15) * 132 + k] = v;
        t[e] = f2bs(v);
      }
      afr[rt][s] = t;
    }
  }
  // dt weights -> LDS
  for (int i = tid; i < 2048; i += 256){
    int h = i >> 7, k = i & 127;
    wdt[h * 132 + k] = wf32[(size_t)(DI + CONVD + h) * DM + k];
  }
  __syncthreads();
  // Phase B: dt in f32 (vectorized)
  for (int idx = tid; idx < 1024; idx += 256){
    int r = idx >> 4, h = idx & 15;
    const f32x4* ur = (const f32x4*)(us + r * 132);
    const f32x4* wr = (const f32x4*)(wdt + h * 132);
    float acc = 0.f;
    #pragma unroll 8
    for (int q = 0; q < 32; ++q){
      f32x4 a = ur[q], b = wr[q];
      acc += a[0]*b[0] + a[1]*b[1] + a[2]*b[2] + a[3]*b[3];
    }
    float tv = acc + dt_bias[h];
    float sp = (tv > 20.f) ? tv : log1pf(__expf(tv));
    dtb[(size_t)(l0 + r) * NH + h] = sp;
  }
  // Phase C: z / xBC via MFMA, staged through LDS for coalesced stores
  int gbase = (c < NCH2) ? 8 : 0;                // first half skips z groups
  int ngroups = (c < NCH2) ? 16 : 24;
  int row = tid >> 2, quad = tid & 3;
  for (int gi = 0; gi < ngroups; ++gi){
    int gg = gi + gbase;                          // group of 4 jt-tiles (64 cols)
    int jt = gg * 4 + wv;
    bool isZ = (gg < 8);
    __syncthreads();                              // stage free (prev group's reads done / dt phase done)
    const unsigned short* wb = wbf + (size_t)(jt * 16 + l15) * DM + kg * 8;
    bf16x8 bfrag[4];
    #pragma unroll
    for (int s = 0; s < 4; ++s) bfrag[s] = *reinterpret_cast<const bf16x8*>(wb + s * 32);
    #pragma unroll
    for (int rt = 0; rt < 4; ++rt){
      f32x4 acc = {0.f, 0.f, 0.f, 0.f};
      #pragma unroll
      for (int s = 0; s < 4; ++s) acc = MFMA16(afr[rt][s], bfrag[s], acc);
      #pragma unroll
      for (int r = 0; r < 4; ++r){
        int lrow = rt * 16 + kg * 4 + r;
        float v = acc[r];
        if (isZ) v = v / (1.f + __expf(-v));      // silu(z)
        stage[lrow * 72 + wv * 16 + l15] = f2b(v);
      }
    }
    __syncthreads();
    const unsigned short* sp = stage + row * 72 + quad * 16;
    uint4 v0 = *reinterpret_cast<const uint4*>(sp);
    uint4 v1 = *reinterpret_cast<const uint4*>(sp + 8);
    unsigned short* dst = isZ
      ? g + (size_t)(l0 + row - HW) * DI + gg * 64 + quad * 16
      : xbcraw + (size_t)(l0 + row) * CONVD + (gg * 64 - DI) + quad * 16;
    *reinterpret_cast<uint4*>(dst) = v0;
    *reinterpret_cast<uint4*>(dst + 8) = v1;
  }
}

// ---------------------------------------------------------------- K3: depthwise causal conv + silu (x4 vectorized)
__global__ __launch_bounds__(256) void k_conv(const unsigned short* __restrict__ raw,
    const float* __restrict__ cw, const float* __restrict__ cb,
    unsigned short* __restrict__ out){
  int idx = blockIdx.x * 256 + threadIdx.x;       // one per 4 channels
  int l = idx >> 8, c4 = (idx & 255) << 2;
  f32x4 wr[4];
  #pragma unroll
  for (int e = 0; e < 4; ++e) wr[e] = *reinterpret_cast<const f32x4*>(cw + (c4 + e) * 4);
  f32x4 bias = *reinterpret_cast<const f32x4*>(cb + c4);
  us4 rv[4];
  #pragma unroll
  for (int t = 0; t < 4; ++t){
    int ll = l - 3 + t;
    if (ll >= 0) rv[t] = *reinterpret_cast<const us4*>(raw + (size_t)ll * CONVD + c4);
    else rv[t] = (us4){0,0,0,0};
  }
  us4 o;
  #pragma unroll
  for (int e = 0; e < 4; ++e){
    f32x4 we = wr[e];
    float acc = bias[e] + b2f(rv[0][e])*we[0] + b2f(rv[1][e])*we[1]
                        + b2f(rv[2][e])*we[2] + b2f(rv[3][e])*we[3];
    o[e] = f2b(acc / (1.f + __expf(-acc)));
  }
  *reinterpret_cast<us4*>(out + (size_t)l * CONVD + c4) = o;
}

// ---------------------------------------------------------------- K4: per-chunk SSD core (MFMA, LDS-staged stores)
__global__ __launch_bounds__(256) void k_chunk(const unsigned short* __restrict__ xbc,
    const float* __restrict__ dtb, const float* __restrict__ A_log,
    unsigned short* __restrict__ states, float* __restrict__ atot,
    float* __restrict__ ecs, unsigned short* __restrict__ ydiag, int cbase){
  __shared__ char U[65536];          // Bs[0,32K) Cs[32K,64K) -> then M/xdtT/xwT/stage
  __shared__ float dts[1024];        // [t*16+h]
  __shared__ float Acs[1024];        // [h*64+t]
  unsigned short* Bs = (unsigned short*)U;
  unsigned short* Cs = (unsigned short*)(U + 32768);
  char* Mb  = U;                                   // [64][64] bf16 swizzled (8KB)
  char* xdT = U + 8192;                            // [32][64] bf16 swizzled (4KB)
  char* xwT = U + 12288;                           // [32][64] bf16 swizzled (4KB)
  unsigned short* stageS = (unsigned short*)(U + 16384);   // [32][264] bf16 (16.9KB)
  unsigned short* stageY = (unsigned short*)(U + 33280);   // [64][40] bf16 (5.1KB)
  int cl = blockIdx.x, c = cbase + cl, l0 = c * 64;
  int tid = threadIdx.x, lane = tid & 63, wv = tid >> 6;
  int kg = lane >> 4, l15 = lane & 15;
  bool doY = (c >= NCH2);

  for (int i = tid; i < 1024; i += 256) dts[i] = dtb[(size_t)l0 * NH + i];
  #pragma unroll
  for (int it = 0; it < 8; ++it){
    int r = (tid >> 5) + 8 * it, c8 = tid & 31;
    uint4 v = *reinterpret_cast<const uint4*>(xbc + (size_t)(l0 + r) * CONVD + DI + c8 * 8);
    *reinterpret_cast<uint4*>((char*)Bs + ((r * 512 + c8 * 16) ^ ((r & 7) << 4))) = v;
    if (doY){
      uint4 v2 = *reinterpret_cast<const uint4*>(xbc + (size_t)(l0 + r) * CONVD + DI + DS + c8 * 8);
      *reinterpret_cast<uint4*>((char*)Cs + ((r * 512 + c8 * 16) ^ ((r & 7) << 4))) = v2;
    }
  }
  __syncthreads();
  if (tid < 16){
    int h = tid; float Ah = -__expf(A_log[h]); float s = 0.f;
    for (int t = 0; t < 64; ++t){ s += dts[t*16 + h] * Ah; Acs[h*64 + t] = s; }
    atot[c * NH + h] = __expf(s);
  }
  // B^T fragments for the state GEMM (k = t), kept in registers for all h
  bf16x8 bst[8];     // [nt*2 + s]
  #pragma unroll
  for (int nt = 0; nt < 4; ++nt)
    #pragma unroll
    for (int s = 0; s < 2; ++s){
      int n = wv * 64 + nt * 16 + l15;
      int tb = s * 32 + kg * 8;
      bf16x8 f;
      #pragma unroll
      for (int e = 0; e < 8; ++e){
        int t = tb + e;
        f[e] = *reinterpret_cast<const short*>((char*)Bs + ((t * 512 + n * 2) ^ ((t & 7) << 4)));
      }
      bst[nt * 2 + s] = f;
    }
  // G = C.B^T (this wave's 16-row t-tile x all 64 s), registers
  f32x4 Gacc[4];
  if (doY){
    #pragma unroll
    for (int st = 0; st < 4; ++st) Gacc[st] = (f32x4){0.f,0.f,0.f,0.f};
    int trow = wv * 16 + l15;
    for (int ks = 0; ks < 8; ++ks){
      bf16x8 a = *reinterpret_cast<const bf16x8*>((char*)Cs + ((trow * 512 + (ks*32 + kg*8) * 2) ^ ((trow & 7) << 4)));
      #pragma unroll
      for (int st = 0; st < 4; ++st){
        int srow = st * 16 + l15;
        bf16x8 b = *reinterpret_cast<const bf16x8*>((char*)Bs + ((srow * 512 + (ks*32 + kg*8) * 2) ^ ((srow & 7) << 4)));
        Gacc[st] = MFMA16(a, b, Gacc[st]);
      }
    }
  }
  __syncthreads();     // Bs/Cs dead; Acs ready
  for (int h = 0; h < NH; ++h){
    float alast = Acs[h*64 + 63];
    {  // write xdt^T (doY only), xw^T  [p][t] bf16 swizzled
      int t = tid & 63, pb = tid >> 6;
      float dtv = dts[t*16 + h];
      float dec = __expf(alast - Acs[h*64 + t]);
      us8 x8 = *reinterpret_cast<const us8*>(xbc + (size_t)(l0 + t) * CONVD + h * HD + pb * 8);
      #pragma unroll
      for (int e = 0; e < 8; ++e){
        int pp = pb * 8 + e;
        float v = b2f(x8[e]) * dtv;
        if (doY) *reinterpret_cast<unsigned short*>(xdT + ((pp * 128 + t * 2) ^ ((pp & 7) << 4))) = f2b(v);
        *reinterpret_cast<unsigned short*>(xwT + ((pp * 128 + t * 2) ^ ((pp & 7) << 4))) = f2b(v * dec);
      }
    }
    if (doY){
      #pragma unroll
      for (int st = 0; st < 4; ++st)
        #pragma unroll
        for (int r = 0; r < 4; ++r){
          int t = wv * 16 + kg * 4 + r, s2 = st * 16 + l15;
          float m = (s2 <= t) ? Gacc[st][r] * __expf(Acs[h*64 + t] - Acs[h*64 + s2]) : 0.f;
          *reinterpret_cast<unsigned short*>(Mb + ((t * 128 + s2 * 2) ^ ((t & 7) << 4))) = f2b(m);
        }
      if (tid < 64) ecs[((size_t)(c - NCH2) * NH + h) * 64 + tid] = __expf(Acs[h*64 + tid]);
    }
    __syncthreads();
    {  // states[p][n] = sum_t xw^T[p][t] * B[t][n] -> stageS
      f32x4 sacc[2][4];
      #pragma unroll
      for (int mt = 0; mt < 2; ++mt)
        #pragma unroll
        for (int nt = 0; nt < 4; ++nt) sacc[mt][nt] = (f32x4){0.f,0.f,0.f,0.f};
      #pragma unroll
      for (int s = 0; s < 2; ++s)
        #pragma unroll
        for (int mt = 0; mt < 2; ++mt){
          int pr = mt * 16 + l15;
          bf16x8 a = *reinterpret_cast<const bf16x8*>(xwT + ((pr * 128 + (s*32 + kg*8) * 2) ^ ((pr & 7) << 4)));
          #pragma unroll
          for (int nt = 0; nt < 4; ++nt) sacc[mt][nt] = MFMA16(a, bst[nt*2 + s], sacc[mt][nt]);
        }
      #pragma unroll
      for (int mt = 0; mt < 2; ++mt)
        #pragma unroll
        for (int nt = 0; nt < 4; ++nt)
          #pragma unroll
          for (int r = 0; r < 4; ++r){
            int pp = mt * 16 + kg * 4 + r, n = wv * 64 + nt * 16 + l15;
            stageS[pp * 264 + n] = f2b(sacc[mt][nt][r]);
          }
    }
    if (doY){  // Y_diag[t][p] = sum_s M[t][s] * xdt^T[p][s] -> stageY
      f32x4 yacc[2];
      yacc[0] = (f32x4){0.f,0.f,0.f,0.f}; yacc[1] = (f32x4){0.f,0.f,0.f,0.f};
      int trow = wv * 16 + l15;
      #pragma unroll
      for (int s = 0; s < 2; ++s){
        bf16x8 a = *reinterpret_cast<const bf16x8*>(Mb + ((trow * 128 + (s*32 + kg*8) * 2) ^ ((trow & 7) << 4)));
        #pragma unroll
        for (int pt = 0; pt < 2; ++pt){
          int pr = pt * 16 + l15;
          bf16x8 b = *reinterpret_cast<const bf16x8*>(xdT + ((pr * 128 + (s*32 + kg*8) * 2) ^ ((pr & 7) << 4)));
          yacc[pt] = MFMA16(a, b, yacc[pt]);
        }
      }
      #pragma unroll
      for (int pt = 0; pt < 2; ++pt)
        #pragma unroll
        for (int r = 0; r < 4; ++r){
          int t = wv * 16 + kg * 4 + r, pp = pt * 16 + l15;
          stageY[t * 40 + pp] = f2b(yacc[pt][r]);
        }
    }
    __syncthreads();
    {  // cooperative coalesced stores
      int row = tid >> 3, seg = tid & 7;           // 32 rows x 8 threads
      const unsigned short* sp = stageS + row * 264 + seg * 32;
      unsigned short* gp = states + (((size_t)cl * NH + h) * HD + row) * DS + seg * 32;
      #pragma unroll
      for (int k = 0; k < 4; ++k)
        *reinterpret_cast<uint4*>(gp + k * 8) = *reinterpret_cast<const uint4*>(sp + k * 8);
      if (doY){
        int rw = tid >> 2, quad = tid & 3;         // 64 rows x 4 threads
        *reinterpret_cast<uint4*>(ydiag + (size_t)(l0 - HW + rw) * DI + h * HD + quad * 8)
          = *reinterpret_cast<const uint4*>(stageY + rw * 40 + quad * 8);
      }
    }
    __syncthreads();
  }
}

// ---------------------------------------------------------------- K5a: reduce first-half states -> carry
__global__ __launch_bounds__(256) void k_scanred(const unsigned short* __restrict__ states,
    const float* __restrict__ atot, float* __restrict__ carry){
  __shared__ float sat[NCH2];
  int idx = blockIdx.x * 256 + threadIdx.x;     // 0..131071, one (h,p,n)
  int h = idx >> 13;
  for (int c = threadIdx.x; c < NCH2; c += 256) sat[c] = atot[c * NH + h];
  __syncthreads();
  float cr = 0.f;
  const unsigned short* p = states + idx;
  for (int c = 0; c < NCH2; ++c){
    cr = sat[c] * cr + b2f(*p);
    p += 131072;
  }
  carry[idx] = cr;
}

// ---------------------------------------------------------------- K5b: in-place prefix over second-half states
__global__ __launch_bounds__(256) void k_scan2(unsigned short* __restrict__ states,
    const float* __restrict__ atot, const float* __restrict__ carry){
  __shared__ float sat[NCH2];
  int idx = blockIdx.x * 256 + threadIdx.x;
  int h = idx >> 13;
  for (int c = threadIdx.x; c < NCH2; c += 256) sat[c] = atot[(NCH2 + c) * NH + h];
  __syncthreads();
  float cr = carry[idx];
  unsigned short* p = states + idx;
  for (int c = 0; c < NCH2; ++c){
    float s = b2f(*p);
    *p = f2b(cr);
    cr = sat[c] * cr + s;
    p += 131072;
  }
}

// ---------------------------------------------------------------- K6: Y_off + skip + gate + sumsq (MFMA, LDS-staged)
__global__ __launch_bounds__(256) void k_yoff(const unsigned short* __restrict__ xbc,
    const unsigned short* __restrict__ states, const float* __restrict__ ecs,
    const float* __restrict__ Dv, unsigned short* __restrict__ y,
    const unsigned short* __restrict__ g, float* __restrict__ rms){
  __shared__ unsigned short stage[64 * 520];   // [64 t][512 h*p] bf16, padded (66.6KB)
  __shared__ float ecs_s[1024];                // [h*64+t]
  int c2 = blockIdx.x;           // 0..399 (local), chunk = c2 + 400
  int c = c2 + NCH2, l0 = c * 64;
  int tid = threadIdx.x, lane = tid & 63, wv = tid >> 6;
  int kg = lane >> 4, l15 = lane & 15;
  for (int i = tid; i < 1024; i += 256) ecs_s[i] = ecs[(size_t)c2 * 1024 + i];
  // C fragments straight from global (one-time, L2)
  bf16x8 aC[8];
  int trow = wv * 16 + l15;
  #pragma unroll
  for (int ks = 0; ks < 8; ++ks)
    aC[ks] = *reinterpret_cast<const bf16x8*>(xbc + (size_t)(l0 + trow) * CONVD + DI + DS + ks * 32 + kg * 8);
  __syncthreads();
  for (int h = 0; h < NH; ++h){
    f32x4 acc[2];
    acc[0] = (f32x4){0.f,0.f,0.f,0.f}; acc[1] = (f32x4){0.f,0.f,0.f,0.f};
    const unsigned short* sb = states + ((size_t)c2 * NH + h) * HD * DS;
    #pragma unroll
    for (int ks = 0; ks < 8; ++ks)
      #pragma unroll
      for (int pt = 0; pt < 2; ++pt){
        bf16x8 b = *reinterpret_cast<const bf16x8*>(sb + (pt * 16 + l15) * DS + ks * 32 + kg * 8);
        acc[pt] = MFMA16(aC[ks], b, acc[pt]);
      }
    float Dh = Dv[h];
    #pragma unroll
    for (int pt = 0; pt < 2; ++pt)
      #pragma unroll
      for (int r = 0; r < 4; ++r){
        int t = wv * 16 + kg * 4 + r, pp = pt * 16 + l15;
        float xh = b2f(xbc[(size_t)(l0 + t) * CONVD + h * HD + pp]);
        stage[t * 520 + h * HD + pp] = f2b(ecs_s[h*64 + t] * acc[pt][r] + Dh * xh);
      }
  }
  __syncthreads();
  // final pass: coalesced gate + sumsq + store
  int row = tid >> 2, quad = tid & 3;           // 64 rows x 4 threads x 128 cols
  const unsigned short* sr = stage + row * 520 + quad * 128;
  size_t obase = (size_t)(c2 * 64 + row) * DI + quad * 128;
  float ss = 0.f;
  #pragma unroll
  for (int k = 0; k < 16; ++k){
    uint4 sv = *reinterpret_cast<const uint4*>(sr + k * 8);
    uint4 yv = *reinterpret_cast<const uint4*>(y + obase + k * 8);
    uint4 gv = *reinterpret_cast<const uint4*>(g + obase + k * 8);
    unsigned int ow[4];
    const unsigned int* svp = (const unsigned int*)&sv;
    const unsigned int* yvp = (const unsigned int*)&yv;
    const unsigned int* gvp = (const unsigned int*)&gv;
    #pragma unroll
    for (int e = 0; e < 4; ++e){
      float v0 = b2f((unsigned short)(svp[e] & 0xffff)) + b2f((unsigned short)(yvp[e] & 0xffff));
      float v1 = b2f((unsigned short)(svp[e] >> 16)) + b2f((unsigned short)(yvp[e] >> 16));
      float y0 = v0 * b2f((unsigned short)(gvp[e] & 0xffff));
      float y1 = v1 * b2f((unsigned short)(gvp[e] >> 16));
      ss += y0 * y0 + y1 * y1;
      ow[e] = (unsigned int)f2b(y0) | ((unsigned int)f2b(y1) << 16);
    }
    uint4 o; o.x = ow[0]; o.y = ow[1]; o.z = ow[2]; o.w = ow[3];
    *reinterpret_cast<uint4*>(y + obase + k * 8) = o;
  }
  ss += __shfl_xor(ss, 1, 64);
  ss += __shfl_xor(ss, 2, 64);
  if (quad == 0) rms[c2 * 64 + row] = rsqrtf(ss / (float)DI + EPSV);
}

// ---------------------------------------------------------------- K7: half[l] = rms * (y . coef)
__global__ __launch_bounds__(256) void k_half(const unsigned short* __restrict__ yg,
    const float* __restrict__ rms, const float* __restrict__ coef,
    float* __restrict__ half_out){
  int wave = threadIdx.x >> 6, lane = threadIdx.x & 63;
  int row = blockIdx.x * 4 + wave;
  if (row >= HW) return;
  const unsigned short* yr = yg + (size_t)row * DI;
  float acc = 0.f;
  for (int i = lane; i < DI; i += 64) acc += b2f(yr[i]) * coef[i];
  #pragma unroll
  for (int off = 32; off; off >>= 1) acc += __shfl_down(acc, off, 64);
  if (lane == 0) half_out[row] = acc * rms[row];
}

// ---------------------------------------------------------------- K8: final fc1
__global__ __launch_bounds__(256) void k_fc1(const float* __restrict__ half_in,
    const float* __restrict__ w, const float* __restrict__ b, float* __restrict__ out){
  int k = blockIdx.x;
  const float* wr = w + (size_t)k * HW;
  float acc = 0.f;
  for (int i = threadIdx.x; i < HW; i += 256) acc += half_in[i] * wr[i];
  __shared__ float red[256];
  red[threadIdx.x] = acc;
  __syncthreads();
  for (int s = 128; s; s >>= 1){
    if (threadIdx.x < s) red[threadIdx.x] += red[threadIdx.x + s];
    __syncthreads();
  }
  if (threadIdx.x == 0) out[k] = red[0] + b[k];
}

// ---------------------------------------------------------------- launch
extern "C" void kernel_launch(void* const* d_in, const int* in_sizes, int n_in,
                              void* d_out, int out_size, void* d_ws, size_t ws_size,
                              hipStream_t stream){
  const float* x      = (const float*)d_in[0];
  const float* fc0_w  = (const float*)d_in[1];
  const float* fc0_b  = (const float*)d_in[2];
  const float* ipw    = (const float*)d_in[3];
  const float* conv_w = (const float*)d_in[4];
  const float* conv_b = (const float*)d_in[5];
  const float* dt_bias= (const float*)d_in[6];
  const float* A_log  = (const float*)d_in[7];
  const float* Dv     = (const float*)d_in[8];
  const float* norm_w = (const float*)d_in[9];
  const float* opw    = (const float*)d_in[10];
  const float* fc1_w  = (const float*)d_in[11];
  const float* fc1_b  = (const float*)d_in[12];
  float* out = (float*)d_out;

  char* ws = (char*)d_ws;
  size_t off = 0;
  float* dtb          = (float*)(ws + off);           off += (size_t)L_ * NH * 4;          // 3.3 MB
  unsigned short* stx = (unsigned short*)(ws + off);  off += (size_t)L_ * CONVD * 2;       // 104.9 MB (xraw, then 400-chunk states)
  unsigned short* xbc = (unsigned short*)(ws + off);  off += (size_t)L_ * CONVD * 2;       // 104.9 MB
  unsigned short* g   = (unsigned short*)(ws + off);  off += (size_t)HW * DI * 2;          // 26.2 MB
  unsigned short* yd  = (unsigned short*)(ws + off);  off += (size_t)HW * DI * 2;          // 26.2 MB
  float* atot         = (float*)(ws + off);           off += (size_t)NCH * NH * 4;
  float* ecs          = (float*)(ws + off);           off += (size_t)NCH2 * NH * 64 * 4;
  float* rms          = (float*)(ws + off);           off += (size_t)HW * 4;
  float* half_buf     = (float*)(ws + off);           off += (size_t)HW * 4;
  float* coef         = (float*)(ws + off);           off += (size_t)DI * 4;
  float* carry        = (float*)(ws + off);           off += (size_t)131072 * 4;
  unsigned short* wbf16 = (unsigned short*)carry;     // alias: wbf16 dead before carry is written

  if (ws_size < off) return;   // diagnostic guard

  k_coef   <<<2, 256, 0, stream>>>(opw, norm_w, coef);
  k_wcvt   <<<(DIP * DM + 255) / 256, 256, 0, stream>>>(ipw, wbf16);
  k_inproj <<<NCH, 256, 0, stream>>>(x, fc0_w, fc0_b, ipw, wbf16, dt_bias, g, stx, dtb);
  k_conv   <<<(L_ * CONVD / 4) / 256, 256, 0, stream>>>(stx, conv_w, conv_b, xbc);
  // stx dead; reuse as 400-chunk state buffer
  k_chunk  <<<NCH2, 256, 0, stream>>>(xbc, dtb, A_log, stx, atot, ecs, yd, 0);
  k_scanred<<<512, 256, 0, stream>>>(stx, atot, carry);
  k_chunk  <<<NCH2, 256, 0, stream>>>(xbc, dtb, A_log, stx, atot, ecs, yd, NCH2);
  k_scan2  <<<512, 256, 0, stream>>>(stx, atot, carry);
  k_yoff   <<<NCH2, 256, 0, stream>>>(xbc, stx, ecs, Dv, yd, g, rms);
  k_half   <<<HW / 4, 256, 0, stream>>>(yd, rms, coef, half_buf);
  k_fc1    <<<DM, 256, 0, stream>>>(half_buf, fc1_w, fc1_b, out);
}

// Round 6
// 489.243 us; speedup vs baseline: 16.5023x; 1.3420x over previous
//
#include <hip/hip_runtime.h>

#define H_ 160
#define W_ 160
#define HW 25600
#define L_ 51200
#define DM 128
#define DI 512
#define DS 256
#define NH 16
#define HD 32
#define CONVD 1024
#define DIP 1552
#define NCH 800      // number of chunks
#define NCH2 400     // chunks per half
#define EPSV 1e-5f

typedef __attribute__((ext_vector_type(8))) short bf16x8;
typedef __attribute__((ext_vector_type(8))) unsigned short us8;
typedef __attribute__((ext_vector_type(4))) unsigned short us4;
typedef __attribute__((ext_vector_type(4))) float f32x4;
#define MFMA16(a,b,c) __builtin_amdgcn_mfma_f32_16x16x32_bf16(a,b,c,0,0,0)

__device__ __forceinline__ float b2f(unsigned short u){
  union{unsigned int i; float f;} v; v.i = ((unsigned int)u) << 16; return v.f;
}
__device__ __forceinline__ unsigned short f2b(float f){
  union{unsigned int i; float f;} v; v.f = f;
  unsigned int r = v.i + 0x7fffu + ((v.i >> 16) & 1u);
  return (unsigned short)(r >> 16);
}

// ---------------------------------------------------------------- K0: coef
__global__ void k_coef(const float* __restrict__ opw, const float* __restrict__ nw,
                       float* __restrict__ coef){
  int i = blockIdx.x * blockDim.x + threadIdx.x;
  if (i >= DI) return;
  float s = 0.f;
  for (int j = 0; j < DM; ++j) s += opw[j * DI + i];
  coef[i] = (s / (float)DM) * nw[i];
}

// ---------------------------------------------------------------- K0b: rank-4 table q[j] = (w.fw0, w.fw1, w.fw2, w.fb)
__global__ __launch_bounds__(256) void k_qtab(const float* __restrict__ ipw,
    const float* __restrict__ fw, const float* __restrict__ fb, float* __restrict__ q){
  int j = blockIdx.x * 256 + threadIdx.x;
  if (j >= DIP) return;
  const float* wr = ipw + (size_t)j * DM;
  float s0 = 0.f, s1 = 0.f, s2 = 0.f, sb = 0.f;
  for (int k = 0; k < DM; ++k){
    float w = wr[k];
    s0 += w * fw[k*3+0]; s1 += w * fw[k*3+1]; s2 += w * fw[k*3+2]; sb += w * fb[k];
  }
  reinterpret_cast<float4*>(q)[j] = make_float4(s0, s1, s2, sb);
}

// ---------------------------------------------------------------- helpers
__device__ __forceinline__ void xrow(const float* __restrict__ x, int l, float* o){
  int i, j;
  if (l < HW){ i = l / W_; j = l % W_; }
  else { int l2 = l - HW; i = (H_ - 1) - l2 / W_; j = (W_ - 1) - l2 % W_; }
  int p = i * W_ + j;
  o[0] = x[p]; o[1] = x[HW + p]; o[2] = x[2*HW + p];
}

// ---------------------------------------------------------------- K2: fused fc0 + in_proj + conv + silu + dt (rank-4)
__global__ __launch_bounds__(256) void k_fused(const float* __restrict__ x,
    const float* __restrict__ q, const float* __restrict__ cw, const float* __restrict__ cb,
    const float* __restrict__ dt_bias,
    unsigned short* __restrict__ g, unsigned short* __restrict__ xbc, float* __restrict__ dtb){
  int r0 = blockIdx.x * 32;          // 1600 blocks, 32 rows each
  int tid = threadIdx.x;
  // --- xBC: conv + silu. items (l4-group, c8): 8 groups x 128 slots
  {
    int c8 = tid & 127, lg = tid >> 7;
    const float4* qv8 = reinterpret_cast<const float4*>(q) + DI + c8 * 8;
    const float4* wv8 = reinterpret_cast<const float4*>(cw) + c8 * 8;
    const float4* cb2 = reinterpret_cast<const float4*>(cb) + c8 * 2;
    float4 bias0 = cb2[0], bias1 = cb2[1];
    float biasv[8] = {bias0.x,bias0.y,bias0.z,bias0.w,bias1.x,bias1.y,bias1.z,bias1.w};
    for (int it = 0; it < 4; ++it){
      int lbase = r0 + (it * 2 + lg) * 4;       // output rows lbase..lbase+3
      float xv[7][3], vf[7];
      #pragma unroll
      for (int k = 0; k < 7; ++k){
        int l = lbase - 3 + k;
        if (l >= 0){ xrow(x, l, xv[k]); vf[k] = 1.f; }
        else { xv[k][0] = xv[k][1] = xv[k][2] = 0.f; vf[k] = 0.f; }
      }
      unsigned int ow[4][4];
      #pragma unroll
      for (int e = 0; e < 8; ++e){
        float4 qv = qv8[e];
        float raw[7];
        #pragma unroll
        for (int k = 0; k < 7; ++k)
          raw[k] = vf[k]*qv.w + xv[k][0]*qv.x + xv[k][1]*qv.y + xv[k][2]*qv.z;
        float4 wv = wv8[e];
        float bias = biasv[e];
        #pragma unroll
        for (int rr = 0; rr < 4; ++rr){
          float acc = bias + raw[rr]*wv.x + raw[rr+1]*wv.y + raw[rr+2]*wv.z + raw[rr+3]*wv.w;
          float s = acc / (1.f + __expf(-acc));
          unsigned int b = f2b(s);
          if (e & 1) ow[rr][e >> 1] |= b << 16;
          else       ow[rr][e >> 1] = b;
        }
      }
      #pragma unroll
      for (int rr = 0; rr < 4; ++rr){
        uint4 o; o.x = ow[rr][0]; o.y = ow[rr][1]; o.z = ow[rr][2]; o.w = ow[rr][3];
        *reinterpret_cast<uint4*>(xbc + (size_t)(lbase + rr) * CONVD + c8 * 8) = o;
      }
    }
  }
  // --- z gate: silu, second half only
  if (r0 >= HW){
    int c8g = tid & 63;
    const float4* qv8 = reinterpret_cast<const float4*>(q) + c8g * 8;
    for (int it = 0; it < 8; ++it){
      int row = it * 4 + (tid >> 6);
      int l = r0 + row;
      float xv[3]; xrow(x, l, xv);
      unsigned int ow[4];
      #pragma unroll
      for (int e = 0; e < 8; ++e){
        float4 qv = qv8[e];
        float raw = qv.w + xv[0]*qv.x + xv[1]*qv.y + xv[2]*qv.z;
        float s = raw / (1.f + __expf(-raw));
        unsigned int b = f2b(s);
        if (e & 1) ow[e >> 1] |= b << 16;
        else       ow[e >> 1] = b;
      }
      uint4 o; o.x = ow[0]; o.y = ow[1]; o.z = ow[2]; o.w = ow[3];
      *reinterpret_cast<uint4*>(g + (size_t)(l - HW) * DI + c8g * 8) = o;
    }
  }
  // --- dt: softplus, f32. 32 rows x 16 h, 2 per thread
  {
    int row = tid >> 3, h2 = (tid & 7) * 2;
    int l = r0 + row;
    float xv[3]; xrow(x, l, xv);
    #pragma unroll
    for (int e = 0; e < 2; ++e){
      int h = h2 + e;
      float4 qv = reinterpret_cast<const float4*>(q)[DI + CONVD + h];
      float raw = qv.w + xv[0]*qv.x + xv[1]*qv.y + xv[2]*qv.z + dt_bias[h];
      float sp = (raw > 20.f) ? raw : log1pf(__expf(raw));
      dtb[(size_t)l * NH + h] = sp;
    }
  }
}

// ---------------------------------------------------------------- K4: per-chunk SSD core (MFMA, LDS-staged stores)
__global__ __launch_bounds__(256) void k_chunk(const unsigned short* __restrict__ xbc,
    const float* __restrict__ dtb, const float* __restrict__ A_log,
    unsigned short* __restrict__ states, float* __restrict__ atot,
    float* __restrict__ ecs, unsigned short* __restrict__ ydiag, int cbase){
  __shared__ char U[65536];          // Bs[0,32K) Cs[32K,64K) -> then M/xdtT/xwT/stage
  __shared__ float dts[1024];        // [t*16+h]
  __shared__ float Acs[1024];        // [h*64+t]
  unsigned short* Bs = (unsigned short*)U;
  unsigned short* Cs = (unsigned short*)(U + 32768);
  char* Mb  = U;                                   // [64][64] bf16 swizzled (8KB)
  char* xdT = U + 8192;                            // [32][64] bf16 swizzled (4KB)
  char* xwT = U + 12288;                           // [32][64] bf16 swizzled (4KB)
  unsigned short* stageS = (unsigned short*)(U + 16384);   // [32][264] bf16 (16.9KB)
  unsigned short* stageY = (unsigned short*)(U + 33280);   // [64][40] bf16 (5.1KB)
  int cl = blockIdx.x, c = cbase + cl, l0 = c * 64;
  int tid = threadIdx.x, lane = tid & 63, wv = tid >> 6;
  int kg = lane >> 4, l15 = lane & 15;
  bool doY = (c >= NCH2);

  for (int i = tid; i < 1024; i += 256) dts[i] = dtb[(size_t)l0 * NH + i];
  #pragma unroll
  for (int it = 0; it < 8; ++it){
    int r = (tid >> 5) + 8 * it, c8 = tid & 31;
    uint4 v = *reinterpret_cast<const uint4*>(xbc + (size_t)(l0 + r) * CONVD + DI + c8 * 8);
    *reinterpret_cast<uint4*>((char*)Bs + ((r * 512 + c8 * 16) ^ ((r & 7) << 4))) = v;
    if (doY){
      uint4 v2 = *reinterpret_cast<const uint4*>(xbc + (size_t)(l0 + r) * CONVD + DI + DS + c8 * 8);
      *reinterpret_cast<uint4*>((char*)Cs + ((r * 512 + c8 * 16) ^ ((r & 7) << 4))) = v2;
    }
  }
  __syncthreads();
  if (tid < 16){
    int h = tid; float Ah = -__expf(A_log[h]); float s = 0.f;
    for (int t = 0; t < 64; ++t){ s += dts[t*16 + h] * Ah; Acs[h*64 + t] = s; }
    atot[c * NH + h] = __expf(s);
  }
  // B^T fragments for the state GEMM (k = t), kept in registers for all h
  bf16x8 bst[8];     // [nt*2 + s]
  #pragma unroll
  for (int nt = 0; nt < 4; ++nt)
    #pragma unroll
    for (int s = 0; s < 2; ++s){
      int n = wv * 64 + nt * 16 + l15;
      int tb = s * 32 + kg * 8;
      bf16x8 f;
      #pragma unroll
      for (int e = 0; e < 8; ++e){
        int t = tb + e;
        f[e] = *reinterpret_cast<const short*>((char*)Bs + ((t * 512 + n * 2) ^ ((t & 7) << 4)));
      }
      bst[nt * 2 + s] = f;
    }
  // G = C.B^T (this wave's 16-row t-tile x all 64 s), registers
  f32x4 Gacc[4];
  if (doY){
    #pragma unroll
    for (int st = 0; st < 4; ++st) Gacc[st] = (f32x4){0.f,0.f,0.f,0.f};
    int trow = wv * 16 + l15;
    for (int ks = 0; ks < 8; ++ks){
      bf16x8 a = *reinterpret_cast<const bf16x8*>((char*)Cs + ((trow * 512 + (ks*32 + kg*8) * 2) ^ ((trow & 7) << 4)));
      #pragma unroll
      for (int st = 0; st < 4; ++st){
        int srow = st * 16 + l15;
        bf16x8 b = *reinterpret_cast<const bf16x8*>((char*)Bs + ((srow * 512 + (ks*32 + kg*8) * 2) ^ ((srow & 7) << 4)));
        Gacc[st] = MFMA16(a, b, Gacc[st]);
      }
    }
  }
  __syncthreads();     // Bs/Cs dead; Acs ready
  for (int h = 0; h < NH; ++h){
    float alast = Acs[h*64 + 63];
    {  // write xdt^T (doY only), xw^T  [p][t] bf16 swizzled
      int t = tid & 63, pb = tid >> 6;
      float dtv = dts[t*16 + h];
      float dec = __expf(alast - Acs[h*64 + t]);
      us8 x8 = *reinterpret_cast<const us8*>(xbc + (size_t)(l0 + t) * CONVD + h * HD + pb * 8);
      #pragma unroll
      for (int e = 0; e < 8; ++e){
        int pp = pb * 8 + e;
        float v = b2f(x8[e]) * dtv;
        if (doY) *reinterpret_cast<unsigned short*>(xdT + ((pp * 128 + t * 2) ^ ((pp & 7) << 4))) = f2b(v);
        *reinterpret_cast<unsigned short*>(xwT + ((pp * 128 + t * 2) ^ ((pp & 7) << 4))) = f2b(v * dec);
      }
    }
    if (doY){
      #pragma unroll
      for (int st = 0; st < 4; ++st)
        #pragma unroll
        for (int r = 0; r < 4; ++r){
          int t = wv * 16 + kg * 4 + r, s2 = st * 16 + l15;
          float m = (s2 <= t) ? Gacc[st][r] * __expf(Acs[h*64 + t] - Acs[h*64 + s2]) : 0.f;
          *reinterpret_cast<unsigned short*>(Mb + ((t * 128 + s2 * 2) ^ ((t & 7) << 4))) = f2b(m);
        }
      if (tid < 64) ecs[((size_t)(c - NCH2) * NH + h) * 64 + tid] = __expf(Acs[h*64 + tid]);
    }
    __syncthreads();
    {  // states[p][n] = sum_t xw^T[p][t] * B[t][n] -> stageS
      f32x4 sacc[2][4];
      #pragma unroll
      for (int mt = 0; mt < 2; ++mt)
        #pragma unroll
        for (int nt = 0; nt < 4; ++nt) sacc[mt][nt] = (f32x4){0.f,0.f,0.f,0.f};
      #pragma unroll
      for (int s = 0; s < 2; ++s)
        #pragma unroll
        for (int mt = 0; mt < 2; ++mt){
          int pr = mt * 16 + l15;
          bf16x8 a = *reinterpret_cast<const bf16x8*>(xwT + ((pr * 128 + (s*32 + kg*8) * 2) ^ ((pr & 7) << 4)));
          #pragma unroll
          for (int nt = 0; nt < 4; ++nt) sacc[mt][nt] = MFMA16(a, bst[nt*2 + s], sacc[mt][nt]);
        }
      #pragma unroll
      for (int mt = 0; mt < 2; ++mt)
        #pragma unroll
        for (int nt = 0; nt < 4; ++nt)
          #pragma unroll
          for (int r = 0; r < 4; ++r){
            int pp = mt * 16 + kg * 4 + r, n = wv * 64 + nt * 16 + l15;
            stageS[pp * 264 + n] = f2b(sacc[mt][nt][r]);
          }
    }
    if (doY){  // Y_diag[t][p] = sum_s M[t][s] * xdt^T[p][s] -> stageY
      f32x4 yacc[2];
      yacc[0] = (f32x4){0.f,0.f,0.f,0.f}; yacc[1] = (f32x4){0.f,0.f,0.f,0.f};
      int trow = wv * 16 + l15;
      #pragma unroll
      for (int s = 0; s < 2; ++s){
        bf16x8 a = *reinterpret_cast<const bf16x8*>(Mb + ((trow * 128 + (s*32 + kg*8) * 2) ^ ((trow & 7) << 4)));
        #pragma unroll
        for (int pt = 0; pt < 2; ++pt){
          int pr = pt * 16 + l15;
          bf16x8 b = *reinterpret_cast<const bf16x8*>(xdT + ((pr * 128 + (s*32 + kg*8) * 2) ^ ((pr & 7) << 4)));
          yacc[pt] = MFMA16(a, b, yacc[pt]);
        }
      }
      #pragma unroll
      for (int pt = 0; pt < 2; ++pt)
        #pragma unroll
        for (int r = 0; r < 4; ++r){
          int t = wv * 16 + kg * 4 + r, pp = pt * 16 + l15;
          stageY[t * 40 + pp] = f2b(yacc[pt][r]);
        }
    }
    __syncthreads();
    {  // cooperative coalesced stores
      int row = tid >> 3, seg = tid & 7;           // 32 rows x 8 threads
      const unsigned short* sp = stageS + row * 264 + seg * 32;
      unsigned short* gp = states + (((size_t)cl * NH + h) * HD + row) * DS + seg * 32;
      #pragma unroll
      for (int k = 0; k < 4; ++k)
        *reinterpret_cast<uint4*>(gp + k * 8) = *reinterpret_cast<const uint4*>(sp + k * 8);
      if (doY){
        int rw = tid >> 2, quad = tid & 3;         // 64 rows x 4 threads
        *reinterpret_cast<uint4*>(ydiag + (size_t)(l0 - HW + rw) * DI + h * HD + quad * 8)
          = *reinterpret_cast<const uint4*>(stageY + rw * 40 + quad * 8);
      }
    }
    __syncthreads();
  }
}

// ---------------------------------------------------------------- K5a: reduce first-half states -> carry
__global__ __launch_bounds__(256) void k_scanred(const unsigned short* __restrict__ states,
    const float* __restrict__ atot, float* __restrict__ carry){
  __shared__ float sat[NCH2];
  int idx = blockIdx.x * 256 + threadIdx.x;     // 0..131071, one (h,p,n)
  int h = idx >> 13;
  for (int c = threadIdx.x; c < NCH2; c += 256) sat[c] = atot[c * NH + h];
  __syncthreads();
  float cr = 0.f;
  const unsigned short* p = states + idx;
  for (int c = 0; c < NCH2; ++c){
    cr = sat[c] * cr + b2f(*p);
    p += 131072;
  }
  carry[idx] = cr;
}

// ---------------------------------------------------------------- K5b: in-place prefix over second-half states
__global__ __launch_bounds__(256) void k_scan2(unsigned short* __restrict__ states,
    const float* __restrict__ atot, const float* __restrict__ carry){
  __shared__ float sat[NCH2];
  int idx = blockIdx.x * 256 + threadIdx.x;
  int h = idx >> 13;
  for (int c = threadIdx.x; c < NCH2; c += 256) sat[c] = atot[(NCH2 + c) * NH + h];
  __syncthreads();
  float cr = carry[idx];
  unsigned short* p = states + idx;
  for (int c = 0; c < NCH2; ++c){
    float s = b2f(*p);
    *p = f2b(cr);
    cr = sat[c] * cr + s;
    p += 131072;
  }
}

// ---------------------------------------------------------------- K6: Y_off + skip + gate + sumsq (MFMA, LDS-staged)
__global__ __launch_bounds__(256) void k_yoff(const unsigned short* __restrict__ xbc,
    const unsigned short* __restrict__ states, const float* __restrict__ ecs,
    const float* __restrict__ Dv, unsigned short* __restrict__ y,
    const unsigned short* __restrict__ g, float* __restrict__ rms){
  __shared__ unsigned short stage[64 * 520];   // [64 t][512 h*p] bf16, padded (66.6KB)
  __shared__ float ecs_s[1024];                // [h*64+t]
  int c2 = blockIdx.x;           // 0..399 (local), chunk = c2 + 400
  int c = c2 + NCH2, l0 = c * 64;
  int tid = threadIdx.x, lane = tid & 63, wv = tid >> 6;
  int kg = lane >> 4, l15 = lane & 15;
  for (int i = tid; i < 1024; i += 256) ecs_s[i] = ecs[(size_t)c2 * 1024 + i];
  // C fragments straight from global (one-time, L2)
  bf16x8 aC[8];
  int trow = wv * 16 + l15;
  #pragma unroll
  for (int ks = 0; ks < 8; ++ks)
    aC[ks] = *reinterpret_cast<const bf16x8*>(xbc + (size_t)(l0 + trow) * CONVD + DI + DS + ks * 32 + kg * 8);
  __syncthreads();
  for (int h = 0; h < NH; ++h){
    f32x4 acc[2];
    acc[0] = (f32x4){0.f,0.f,0.f,0.f}; acc[1] = (f32x4){0.f,0.f,0.f,0.f};
    const unsigned short* sb = states + ((size_t)c2 * NH + h) * HD * DS;
    #pragma unroll
    for (int ks = 0; ks < 8; ++ks)
      #pragma unroll
      for (int pt = 0; pt < 2; ++pt){
        bf16x8 b = *reinterpret_cast<const bf16x8*>(sb + (pt * 16 + l15) * DS + ks * 32 + kg * 8);
        acc[pt] = MFMA16(aC[ks], b, acc[pt]);
      }
    float Dh = Dv[h];
    #pragma unroll
    for (int pt = 0; pt < 2; ++pt)
      #pragma unroll
      for (int r = 0; r < 4; ++r){
        int t = wv * 16 + kg * 4 + r, pp = pt * 16 + l15;
        float xh = b2f(xbc[(size_t)(l0 + t) * CONVD + h * HD + pp]);
        stage[t * 520 + h * HD + pp] = f2b(ecs_s[h*64 + t] * acc[pt][r] + Dh * xh);
      }
  }
  __syncthreads();
  // final pass: coalesced gate + sumsq + store
  int row = tid >> 2, quad = tid & 3;           // 64 rows x 4 threads x 128 cols
  const unsigned short* sr = stage + row * 520 + quad * 128;
  size_t obase = (size_t)(c2 * 64 + row) * DI + quad * 128;
  float ss = 0.f;
  #pragma unroll
  for (int k = 0; k < 16; ++k){
    uint4 sv = *reinterpret_cast<const uint4*>(sr + k * 8);
    uint4 yv = *reinterpret_cast<const uint4*>(y + obase + k * 8);
    uint4 gv = *reinterpret_cast<const uint4*>(g + obase + k * 8);
    unsigned int ow[4];
    const unsigned int* svp = (const unsigned int*)&sv;
    const unsigned int* yvp = (const unsigned int*)&yv;
    const unsigned int* gvp = (const unsigned int*)&gv;
    #pragma unroll
    for (int e = 0; e < 4; ++e){
      float v0 = b2f((unsigned short)(svp[e] & 0xffff)) + b2f((unsigned short)(yvp[e] & 0xffff));
      float v1 = b2f((unsigned short)(svp[e] >> 16)) + b2f((unsigned short)(yvp[e] >> 16));
      float y0 = v0 * b2f((unsigned short)(gvp[e] & 0xffff));
      float y1 = v1 * b2f((unsigned short)(gvp[e] >> 16));
      ss += y0 * y0 + y1 * y1;
      ow[e] = (unsigned int)f2b(y0) | ((unsigned int)f2b(y1) << 16);
    }
    uint4 o; o.x = ow[0]; o.y = ow[1]; o.z = ow[2]; o.w = ow[3];
    *reinterpret_cast<uint4*>(y + obase + k * 8) = o;
  }
  ss += __shfl_xor(ss, 1, 64);
  ss += __shfl_xor(ss, 2, 64);
  if (quad == 0) rms[c2 * 64 + row] = rsqrtf(ss / (float)DI + EPSV);
}

// ---------------------------------------------------------------- K7: half[l] = rms * (y . coef)
__global__ __launch_bounds__(256) void k_half(const unsigned short* __restrict__ yg,
    const float* __restrict__ rms, const float* __restrict__ coef,
    float* __restrict__ half_out){
  int wave = threadIdx.x >> 6, lane = threadIdx.x & 63;
  int row = blockIdx.x * 4 + wave;
  if (row >= HW) return;
  const unsigned short* yr = yg + (size_t)row * DI;
  float acc = 0.f;
  for (int i = lane; i < DI; i += 64) acc += b2f(yr[i]) * coef[i];
  #pragma unroll
  for (int off = 32; off; off >>= 1) acc += __shfl_down(acc, off, 64);
  if (lane == 0) half_out[row] = acc * rms[row];
}

// ---------------------------------------------------------------- K8: final fc1
__global__ __launch_bounds__(256) void k_fc1(const float* __restrict__ half_in,
    const float* __restrict__ w, const float* __restrict__ b, float* __restrict__ out){
  int k = blockIdx.x;
  const float* wr = w + (size_t)k * HW;
  float acc = 0.f;
  for (int i = threadIdx.x; i < HW; i += 256) acc += half_in[i] * wr[i];
  __shared__ float red[256];
  red[threadIdx.x] = acc;
  __syncthreads();
  for (int s = 128; s; s >>= 1){
    if (threadIdx.x < s) red[threadIdx.x] += red[threadIdx.x + s];
    __syncthreads();
  }
  if (threadIdx.x == 0) out[k] = red[0] + b[k];
}

// ---------------------------------------------------------------- launch
extern "C" void kernel_launch(void* const* d_in, const int* in_sizes, int n_in,
                              void* d_out, int out_size, void* d_ws, size_t ws_size,
                              hipStream_t stream){
  const float* x      = (const float*)d_in[0];
  const float* fc0_w  = (const float*)d_in[1];
  const float* fc0_b  = (const float*)d_in[2];
  const float* ipw    = (const float*)d_in[3];
  const float* conv_w = (const float*)d_in[4];
  const float* conv_b = (const float*)d_in[5];
  const float* dt_bias= (const float*)d_in[6];
  const float* A_log  = (const float*)d_in[7];
  const float* Dv     = (const float*)d_in[8];
  const float* norm_w = (const float*)d_in[9];
  const float* opw    = (const float*)d_in[10];
  const float* fc1_w  = (const float*)d_in[11];
  const float* fc1_b  = (const float*)d_in[12];
  float* out = (float*)d_out;

  char* ws = (char*)d_ws;
  size_t off = 0;
  float* dtb          = (float*)(ws + off);           off += (size_t)L_ * NH * 4;          // 3.3 MB
  unsigned short* stx = (unsigned short*)(ws + off);  off += (size_t)L_ * CONVD * 2;       // 104.9 MB (400-chunk state buffer)
  unsigned short* xbc = (unsigned short*)(ws + off);  off += (size_t)L_ * CONVD * 2;       // 104.9 MB
  unsigned short* g   = (unsigned short*)(ws + off);  off += (size_t)HW * DI * 2;          // 26.2 MB
  unsigned short* yd  = (unsigned short*)(ws + off);  off += (size_t)HW * DI * 2;          // 26.2 MB
  float* atot         = (float*)(ws + off);           off += (size_t)NCH * NH * 4;
  float* ecs          = (float*)(ws + off);           off += (size_t)NCH2 * NH * 64 * 4;
  float* rms          = (float*)(ws + off);           off += (size_t)HW * 4;
  float* half_buf     = (float*)(ws + off);           off += (size_t)HW * 4;
  float* coef         = (float*)(ws + off);           off += (size_t)DI * 4;
  float* carry        = (float*)(ws + off);           off += (size_t)131072 * 4;
  float* qtab         = (float*)(ws + off);           off += (size_t)DIP * 4 * 4;

  if (ws_size < off) return;   // diagnostic guard

  k_coef   <<<2, 256, 0, stream>>>(opw, norm_w, coef);
  k_qtab   <<<(DIP + 255) / 256, 256, 0, stream>>>(ipw, fc0_w, fc0_b, qtab);
  k_fused  <<<L_ / 32, 256, 0, stream>>>(x, qtab, conv_w, conv_b, dt_bias, g, xbc, dtb);
  k_chunk  <<<NCH2, 256, 0, stream>>>(xbc, dtb, A_log, stx, atot, ecs, yd, 0);
  k_scanred<<<512, 256, 0, stream>>>(stx, atot, carry);
  k_chunk  <<<NCH2, 256, 0, stream>>>(xbc, dtb, A_log, stx, atot, ecs, yd, NCH2);
  k_scan2  <<<512, 256, 0, stream>>>(stx, atot, carry);
  k_yoff   <<<NCH2, 256, 0, stream>>>(xbc, stx, ecs, Dv, yd, g, rms);
  k_half   <<<HW / 4, 256, 0, stream>>>(yd, rms, coef, half_buf);
  k_fc1    <<<DM, 256, 0, stream>>>(half_buf, fc1_w, fc1_b, out);
}